// Round 1
// baseline (255.470 us; speedup 1.0000x reference)
//
#include <hip/hip_runtime.h>
#include <hip/hip_bf16.h>
#include <stdint.h>

// BiaffineLabelAttention: out[b,l,i,o] = sum_d head[b,i,d]*U[l,d]*dep[b,o,d]
//                                        + t2h[b,l,i] + t2d[b,l,o] + bias[l]
// B=16, S=256, D=768, L=32.  out = (16,32,256,256) fp32.
//
// Strategy: 512 GEMMs of (head .* U[l]) [256x768] @ dep[b]^T [768x256] in bf16
// MFMA (m97 structure: 128x128 tile / 256 threads / 16x16x32 mfma,
// global_load_lds for the dep tile, manual scale+pack staging for head tile).
// t2 terms + bias added in fp32 epilogue. Prep kernel converts dep->bf16 and
// computes t2h/t2d.

#define B_ 16
#define S_ 256
#define D_ 768
#define L_ 32

typedef unsigned short ushort_t;
typedef __attribute__((ext_vector_type(4))) float f32x4;
typedef __attribute__((ext_vector_type(8))) short s16x8;

typedef __attribute__((address_space(1))) const unsigned int guint;
typedef __attribute__((address_space(3))) unsigned int luint;

__device__ __forceinline__ void async_load16(const ushort_t* g, ushort_t* l) {
  __builtin_amdgcn_global_load_lds((guint*)g, (luint*)l, 16, 0, 0);
}

// round-half-up fp32->bf16 pair pack: 3 VALU ops (add, add, v_perm)
__device__ __forceinline__ unsigned int pack_bf16(float f0, float f1) {
  unsigned int u0 = __builtin_bit_cast(unsigned int, f0) + 0x8000u;
  unsigned int u1 = __builtin_bit_cast(unsigned int, f1) + 0x8000u;
  return __builtin_amdgcn_perm(u1, u0, 0x07060302);
}

// ---------------------------------------------------------------------------
// Prep: t2h[b,l,i] = sum_d Wh[l,d]*head[b,i,d]; t2d likewise from dep.
// sel==1 blocks also emit depb (bf16 copy of dep).
// grid = B * 2(sel) * 4(i-chunks of 64), block = 256.
// ---------------------------------------------------------------------------
__global__ __launch_bounds__(256) void prep_kernel(
    const float* __restrict__ head, const float* __restrict__ dep,
    const float* __restrict__ labelW,
    ushort_t* __restrict__ depb,
    float* __restrict__ t2h, float* __restrict__ t2d) {
  __shared__ float Ss[64][64];   // [dd][i] — column reads conflict-free
  __shared__ float Ws[32][65];   // pad 65: lg*4*65 % 32 = lg*4 -> conflict-free

  const int z = blockIdx.x;
  const int ic = z & 3;
  const int sel = (z >> 2) & 1;
  const int b = z >> 3;
  const int i0 = ic * 64;
  const float* src = sel ? dep : head;
  float* t2x = sel ? t2d : t2h;
  const int t = threadIdx.x;

  // compute decomposition: 2 i's x 4 l's per thread
  const int ig = t >> 3;       // 0..31
  const int lg = t & 7;        // 0..7
  float acc[2][4] = {{0.f, 0.f, 0.f, 0.f}, {0.f, 0.f, 0.f, 0.f}};

  // staging decomposition: row = t/4 (0..63), 16 consecutive d per thread
  const int srow = t >> 2;
  const int sd0 = (t & 3) * 16;

  for (int dc = 0; dc < D_; dc += 64) {
    __syncthreads();
    {  // stage W chunk: l = t/8, 8 d per thread
      const int wl = t >> 3, wd0 = (t & 7) * 8;
      const float* wp = labelW + (size_t)wl * (2 * D_) + sel * D_ + dc + wd0;
#pragma unroll
      for (int j = 0; j < 8; ++j) Ws[wl][wd0 + j] = wp[j];
    }
    {  // stage src chunk transposed into Ss[dd][i]; emit bf16 if sel
      const float* sp = src + ((size_t)(b * S_ + i0 + srow)) * D_ + dc + sd0;
      float4 v0 = *(const float4*)(sp);
      float4 v1 = *(const float4*)(sp + 4);
      float4 v2 = *(const float4*)(sp + 8);
      float4 v3 = *(const float4*)(sp + 12);
      float arr[16] = {v0.x, v0.y, v0.z, v0.w, v1.x, v1.y, v1.z, v1.w,
                       v2.x, v2.y, v2.z, v2.w, v3.x, v3.y, v3.z, v3.w};
#pragma unroll
      for (int j = 0; j < 16; ++j) Ss[sd0 + j][srow] = arr[j];
      if (sel) {
        unsigned int pk[8];
#pragma unroll
        for (int j = 0; j < 8; ++j) pk[j] = pack_bf16(arr[2 * j], arr[2 * j + 1]);
        unsigned int* dp =
            (unsigned int*)(depb + ((size_t)(b * S_ + i0 + srow)) * D_ + dc + sd0);
        uint4 w0 = {pk[0], pk[1], pk[2], pk[3]};
        uint4 w1 = {pk[4], pk[5], pk[6], pk[7]};
        *(uint4*)(dp) = w0;
        *(uint4*)(dp + 4) = w1;
      }
    }
    __syncthreads();
#pragma unroll 4
    for (int dd = 0; dd < 64; ++dd) {
      const float s0 = Ss[dd][ig * 2 + 0];
      const float s1 = Ss[dd][ig * 2 + 1];
#pragma unroll
      for (int j = 0; j < 4; ++j) {
        const float w = Ws[lg * 4 + j][dd];
        acc[0][j] += s0 * w;
        acc[1][j] += s1 * w;
      }
    }
  }
#pragma unroll
  for (int j = 0; j < 4; ++j) {
    const int l = lg * 4 + j;
    float* op = t2x + ((size_t)(b * L_ + l)) * S_ + i0 + ig * 2;
    op[0] = acc[0][j];
    op[1] = acc[1][j];
  }
}

// ---------------------------------------------------------------------------
// Main: per block one (b,l) and one 128x128 tile of the 256x256 output.
// grid = B*L*4 = 2048 blocks, 256 threads (4 waves, each 64x64 = 4x4 mfma).
// ---------------------------------------------------------------------------
__global__ __launch_bounds__(256) void main_kernel(
    const float* __restrict__ head, const ushort_t* __restrict__ depb,
    const float* __restrict__ U, const float* __restrict__ bias,
    const float* __restrict__ t2h, const float* __restrict__ t2d,
    float* __restrict__ out) {
  __shared__ ushort_t As[128 * 32];  // [row][k] packed bf16, 8 KB
  __shared__ ushort_t Bs[128 * 32];
  __shared__ float Us[D_];           // U[l,:] fp32, 3 KB
  __shared__ float T2[256];          // [0:128]=t2h rows, [128:256]=t2d cols

  const int bid = blockIdx.x;
  const int tile = bid & 3;
  const int bl = bid >> 2;
  const int l = bl & (L_ - 1);
  const int b = bl >> 5;
  const int ti = (tile >> 1) * 128;
  const int to = (tile & 1) * 128;
  const int t = threadIdx.x;
  const int lane = t & 63;
  const int wave = t >> 6;
  const int m_base = (wave >> 1) * 64;
  const int n_base = (wave & 1) * 64;

  for (int i = t; i < D_ / 4; i += 256)
    ((float4*)Us)[i] = ((const float4*)(U + (size_t)l * D_))[i];
  if (t < 128)
    T2[t] = t2h[((size_t)(b * L_ + l)) * S_ + ti + t];
  else
    T2[t] = t2d[((size_t)(b * L_ + l)) * S_ + to + (t - 128)];
  const float bv = bias[l];

  // staging: chunk c covers (row=c/4, k-quad=(c%4)*8); rounds c=t and c=t+256
  const int row0 = t >> 2;
  const int kq = (t & 3) * 8;
  const float* hp0 = head + ((size_t)(b * S_ + ti + row0)) * D_ + kq;
  const float* hp1 = hp0 + (size_t)64 * D_;
  const ushort_t* dp0 = depb + ((size_t)(b * S_ + to + row0)) * D_ + kq;
  const ushort_t* dp1 = dp0 + (size_t)64 * D_;
  ushort_t* asw0 = As + t * 8;
  ushort_t* asw1 = As + (256 + t) * 8;
  ushort_t* bsw0 = Bs + t * 8;
  ushort_t* bsw1 = Bs + (256 + t) * 8;

  f32x4 acc[4][4];
#pragma unroll
  for (int i = 0; i < 4; ++i)
#pragma unroll
    for (int j = 0; j < 4; ++j) acc[i][j] = {0.f, 0.f, 0.f, 0.f};

  const ushort_t* ar = As + ((m_base + (lane & 15)) * 32 + (lane >> 4) * 8);
  const ushort_t* br = Bs + ((n_base + (lane & 15)) * 32 + (lane >> 4) * 8);

  for (int kk = 0; kk < D_; kk += 32) {
    __syncthreads();  // prior iteration's frag reads done
    // B tile: async DMA, 2 x 16B per thread
    async_load16(dp0 + kk, bsw0);
    async_load16(dp1 + kk, bsw1);
    // A tile: load fp32 head, scale by U, pack bf16, 2 x 16B LDS stores
    float4 h0 = *(const float4*)(hp0 + kk);
    float4 h1 = *(const float4*)(hp0 + kk + 4);
    float4 h2 = *(const float4*)(hp1 + kk);
    float4 h3 = *(const float4*)(hp1 + kk + 4);
    float4 u0 = *(const float4*)(Us + kk + kq);
    float4 u1 = *(const float4*)(Us + kk + kq + 4);
    uint4 w0, w1;
    w0.x = pack_bf16(h0.x * u0.x, h0.y * u0.y);
    w0.y = pack_bf16(h0.z * u0.z, h0.w * u0.w);
    w0.z = pack_bf16(h1.x * u1.x, h1.y * u1.y);
    w0.w = pack_bf16(h1.z * u1.z, h1.w * u1.w);
    w1.x = pack_bf16(h2.x * u0.x, h2.y * u0.y);
    w1.y = pack_bf16(h2.z * u0.z, h2.w * u0.w);
    w1.z = pack_bf16(h3.x * u1.x, h3.y * u1.y);
    w1.w = pack_bf16(h3.z * u1.z, h3.w * u1.w);
    *(uint4*)asw0 = w0;
    *(uint4*)asw1 = w1;
    __syncthreads();  // staging (incl. async DMA) visible

    s16x8 af[4], bf[4];
#pragma unroll
    for (int rt = 0; rt < 4; ++rt) af[rt] = *(const s16x8*)(ar + rt * 16 * 32);
#pragma unroll
    for (int ct = 0; ct < 4; ++ct) bf[ct] = *(const s16x8*)(br + ct * 16 * 32);
#pragma unroll
    for (int rt = 0; rt < 4; ++rt)
#pragma unroll
      for (int ct = 0; ct < 4; ++ct)
        acc[rt][ct] = __builtin_amdgcn_mfma_f32_16x16x32_bf16(af[rt], bf[ct],
                                                              acc[rt][ct], 0, 0, 0);
  }

  // epilogue: C/D layout col=lane&15, row=(lane>>4)*4+reg (m89-verified)
  const int colg = lane & 15;
  const int rgrp = lane >> 4;
  float* ob = out + (((size_t)(b * L_ + l)) * S_ + ti) * S_ + to;
#pragma unroll
  for (int rt = 0; rt < 4; ++rt) {
    const int r0 = m_base + rt * 16 + rgrp * 4;
#pragma unroll
    for (int ct = 0; ct < 4; ++ct) {
      const int c = n_base + ct * 16 + colg;
      const float addc = T2[128 + c] + bv;
      float* p = ob + (size_t)r0 * S_ + c;
#pragma unroll
      for (int r = 0; r < 4; ++r)
        p[(size_t)r * S_] = acc[rt][ct][r] + T2[r0 + r] + addc;
    }
  }
}

extern "C" void kernel_launch(void* const* d_in, const int* in_sizes, int n_in,
                              void* d_out, int out_size, void* d_ws, size_t ws_size,
                              hipStream_t stream) {
  const float* head = (const float*)d_in[0];
  const float* dep = (const float*)d_in[1];
  const float* U = (const float*)d_in[2];
  const float* W = (const float*)d_in[3];
  const float* bias = (const float*)d_in[4];
  float* out = (float*)d_out;

  ushort_t* depb = (ushort_t*)d_ws;                          // 6,291,456 B
  float* t2h = (float*)((char*)d_ws + (size_t)B_ * S_ * D_ * 2);
  float* t2d = t2h + (size_t)B_ * L_ * S_;                   // +524,288 B each

  prep_kernel<<<B_ * 2 * 4, 256, 0, stream>>>(head, dep, W, depb, t2h, t2d);
  main_kernel<<<B_ * L_ * 4, 256, 0, stream>>>(head, depb, U, bias, t2h, t2d, out);
}

// Round 2
// 249.388 us; speedup vs baseline: 1.0244x; 1.0244x over previous
//
#include <hip/hip_runtime.h>
#include <hip/hip_bf16.h>
#include <stdint.h>

// out[b,l,i,o] = sum_d head[b,i,d]*U[l,d]*dep[b,o,d] + t2h[b,l,i] + t2d[b,l,o] + b[l]
// B=16, S=256, D=768, L=32. out (16,32,256,256) fp32.
//
// R2: main = 128x256 block tile (grid B*L*2), wave tile 64x128 (4x8 mfma
// 16x16x32), dep DMA'd bf16 via global_load_lds, head scaled by U + packed to
// bf16 in registers, U read from global (L1). prep = wave-per-4-rows shuffle
// kernel (no LDS), computes t2h/t2d + bf16 dep copy.

#define B_ 16
#define S_ 256
#define D_ 768
#define L_ 32

typedef unsigned short ushort_t;
typedef __attribute__((ext_vector_type(4))) float f32x4;
typedef __attribute__((ext_vector_type(8))) short s16x8;

typedef __attribute__((address_space(1))) const unsigned int guint;
typedef __attribute__((address_space(3))) unsigned int luint;

__device__ __forceinline__ void async_load16(const ushort_t* g, ushort_t* l) {
  __builtin_amdgcn_global_load_lds((guint*)g, (luint*)l, 16, 0, 0);
}

// round-half-up fp32->bf16 pair pack; f0 -> low half, f1 -> high half
__device__ __forceinline__ unsigned int pack_bf16(float f0, float f1) {
  unsigned int u0 = __builtin_bit_cast(unsigned int, f0) + 0x8000u;
  unsigned int u1 = __builtin_bit_cast(unsigned int, f1) + 0x8000u;
  return __builtin_amdgcn_perm(u1, u0, 0x07060302);
}

// ---------------------------------------------------------------------------
// Prep: one wave per 4 rows. Lane owns 12 d's in registers. t2 dots via
// per-lane FMA + butterfly shuffle reduce. dep waves also emit bf16 depb.
// grid = 512 blocks x 256 thr = 2048 waves = B*S*2/4 rows.
// ---------------------------------------------------------------------------
__global__ __launch_bounds__(256) void prep_kernel(
    const float* __restrict__ head, const float* __restrict__ dep,
    const float* __restrict__ labelW, ushort_t* __restrict__ depb,
    float* __restrict__ t2h, float* __restrict__ t2d) {
  const int wave = threadIdx.x >> 6;
  const int lane = threadIdx.x & 63;
  const int g = blockIdx.x * 4 + wave;  // 0..2047
  const int sel = g >> 10;              // 0=head, 1=dep
  const int idx = g & 1023;
  const int b = idx >> 6;
  const int row0 = (idx & 63) * 4;
  const float* src = sel ? dep : head;
  float* t2x = sel ? t2d : t2h;
  const int d0 = lane * 12;

  float h[4][12];
  const float* rp = src + ((size_t)(b * S_ + row0)) * D_ + d0;
#pragma unroll
  for (int r = 0; r < 4; ++r) {
    float4 v0 = *(const float4*)(rp + (size_t)r * D_);
    float4 v1 = *(const float4*)(rp + (size_t)r * D_ + 4);
    float4 v2 = *(const float4*)(rp + (size_t)r * D_ + 8);
    h[r][0] = v0.x; h[r][1] = v0.y; h[r][2] = v0.z; h[r][3] = v0.w;
    h[r][4] = v1.x; h[r][5] = v1.y; h[r][6] = v1.z; h[r][7] = v1.w;
    h[r][8] = v2.x; h[r][9] = v2.y; h[r][10] = v2.z; h[r][11] = v2.w;
  }
  if (sel) {
#pragma unroll
    for (int r = 0; r < 4; ++r) {
      uint2 q0 = {pack_bf16(h[r][0], h[r][1]), pack_bf16(h[r][2], h[r][3])};
      uint2 q1 = {pack_bf16(h[r][4], h[r][5]), pack_bf16(h[r][6], h[r][7])};
      uint2 q2 = {pack_bf16(h[r][8], h[r][9]), pack_bf16(h[r][10], h[r][11])};
      uint2* dp = (uint2*)(depb + ((size_t)(b * S_ + row0 + r)) * D_ + d0);
      dp[0] = q0; dp[1] = q1; dp[2] = q2;
    }
  }
  const float* wbase = labelW + sel * D_ + d0;
  for (int l = 0; l < L_; ++l) {
    const float* wp = wbase + (size_t)l * (2 * D_);
    float4 w0 = *(const float4*)(wp);
    float4 w1 = *(const float4*)(wp + 4);
    float4 w2 = *(const float4*)(wp + 8);
    float w[12] = {w0.x, w0.y, w0.z, w0.w, w1.x, w1.y, w1.z, w1.w,
                   w2.x, w2.y, w2.z, w2.w};
    float p0 = 0.f, p1 = 0.f, p2 = 0.f, p3 = 0.f;
#pragma unroll
    for (int j = 0; j < 12; ++j) {
      p0 += h[0][j] * w[j];
      p1 += h[1][j] * w[j];
      p2 += h[2][j] * w[j];
      p3 += h[3][j] * w[j];
    }
#pragma unroll
    for (int off = 32; off >= 1; off >>= 1) {
      p0 += __shfl_xor(p0, off);
      p1 += __shfl_xor(p1, off);
      p2 += __shfl_xor(p2, off);
      p3 += __shfl_xor(p3, off);
    }
    if (lane < 4) {
      float v = lane == 0 ? p0 : lane == 1 ? p1 : lane == 2 ? p2 : p3;
      t2x[((size_t)(b * L_ + l)) * S_ + row0 + lane] = v;
    }
  }
}

// ---------------------------------------------------------------------------
// Main: block = (b, l, i-half). Tile 128(i) x 256(o), 4 waves of 64x128.
// grid = B*L*2 = 1024 blocks, 256 threads.
// ---------------------------------------------------------------------------
__global__ __launch_bounds__(256, 2) void main_kernel(
    const float* __restrict__ head, const ushort_t* __restrict__ depb,
    const float* __restrict__ U, const float* __restrict__ bias,
    const float* __restrict__ t2h, const float* __restrict__ t2d,
    float* __restrict__ out) {
  __shared__ ushort_t As[128 * 32];  // 8 KB  [row][k] bf16
  __shared__ ushort_t Bs[256 * 32];  // 16 KB [col][k] bf16
  __shared__ float T2[384];          // [0:128]=t2h tile rows, [128:384]=t2d all cols

  const int bid = blockIdx.x;
  const int ic = bid & 1;
  const int bl = bid >> 1;
  const int l = bl & (L_ - 1);
  const int b = bl >> 5;
  const int ti = ic * 128;
  const int t = threadIdx.x;
  const int lane = t & 63;
  const int wave = t >> 6;
  const int m_base = (wave >> 1) * 64;
  const int n_base = (wave & 1) * 128;

  for (int i = t; i < 384; i += 256)
    T2[i] = (i < 128) ? t2h[((size_t)(b * L_ + l)) * S_ + ti + i]
                      : t2d[((size_t)(b * L_ + l)) * S_ + (i - 128)];
  const float bv = bias[l];

  // staging decomposition: row0 = t>>2 (0..63), kq = (t&3)*8
  const int row0 = t >> 2;
  const int kq = (t & 3) * 8;
  const float* hp0 = head + ((size_t)(b * S_ + ti + row0)) * D_ + kq;
  const float* hp1 = hp0 + (size_t)64 * D_;
  const float* Up = U + (size_t)l * D_ + kq;
  const ushort_t* dp = depb + ((size_t)(b * S_ + row0)) * D_ + kq;
  ushort_t* asw0 = As + t * 8;
  ushort_t* asw1 = As + t * 8 + 2048;

  f32x4 acc[4][8];
#pragma unroll
  for (int i = 0; i < 4; ++i)
#pragma unroll
    for (int j = 0; j < 8; ++j) acc[i][j] = {0.f, 0.f, 0.f, 0.f};

  const ushort_t* ar = As + ((m_base + (lane & 15)) * 32 + (lane >> 4) * 8);
  const ushort_t* br = Bs + ((n_base + (lane & 15)) * 32 + (lane >> 4) * 8);

  for (int kk = 0; kk < D_; kk += 32) {
    __syncthreads();  // prior iteration's frag reads complete
    // B tile (256 x 32 bf16 = 16 KB): 4 async DMA chunks of 64 rows
#pragma unroll
    for (int j = 0; j < 4; ++j)
      async_load16(dp + kk + (size_t)j * 64 * D_, Bs + j * 2048 + t * 8);
    // A tile: fp32 head * U -> bf16, 2 rows x 8 k per thread
    float4 h0 = *(const float4*)(hp0 + kk);
    float4 h1 = *(const float4*)(hp0 + kk + 4);
    float4 h2 = *(const float4*)(hp1 + kk);
    float4 h3 = *(const float4*)(hp1 + kk + 4);
    float4 u0 = *(const float4*)(Up + kk);
    float4 u1 = *(const float4*)(Up + kk + 4);
    uint4 w0, w1;
    w0.x = pack_bf16(h0.x * u0.x, h0.y * u0.y);
    w0.y = pack_bf16(h0.z * u0.z, h0.w * u0.w);
    w0.z = pack_bf16(h1.x * u1.x, h1.y * u1.y);
    w0.w = pack_bf16(h1.z * u1.z, h1.w * u1.w);
    w1.x = pack_bf16(h2.x * u0.x, h2.y * u0.y);
    w1.y = pack_bf16(h2.z * u0.z, h2.w * u0.w);
    w1.z = pack_bf16(h3.x * u1.x, h3.y * u1.y);
    w1.w = pack_bf16(h3.z * u1.z, h3.w * u1.w);
    *(uint4*)asw0 = w0;
    *(uint4*)asw1 = w1;
    __syncthreads();  // staging (incl. DMA) visible

    s16x8 af[4], bf[8];
#pragma unroll
    for (int rt = 0; rt < 4; ++rt) af[rt] = *(const s16x8*)(ar + rt * 512);
#pragma unroll
    for (int ct = 0; ct < 8; ++ct) bf[ct] = *(const s16x8*)(br + ct * 512);
#pragma unroll
    for (int rt = 0; rt < 4; ++rt)
#pragma unroll
      for (int ct = 0; ct < 8; ++ct)
        acc[rt][ct] = __builtin_amdgcn_mfma_f32_16x16x32_bf16(af[rt], bf[ct],
                                                              acc[rt][ct], 0, 0, 0);
  }

  // epilogue: C/D layout col=lane&15, row=(lane>>4)*4+reg
  const int colg = lane & 15;
  const int rgrp = lane >> 4;
  float* ob = out + (((size_t)(b * L_ + l)) * S_ + ti) * S_;
#pragma unroll
  for (int rt = 0; rt < 4; ++rt) {
    const int r0 = m_base + rt * 16 + rgrp * 4;
#pragma unroll
    for (int ct = 0; ct < 8; ++ct) {
      const int c = n_base + ct * 16 + colg;
      const float addc = T2[128 + c] + bv;
      float* p = ob + (size_t)r0 * S_ + c;
#pragma unroll
      for (int r = 0; r < 4; ++r)
        p[(size_t)r * S_] = acc[rt][ct][r] + T2[r0 + r] + addc;
    }
  }
}

extern "C" void kernel_launch(void* const* d_in, const int* in_sizes, int n_in,
                              void* d_out, int out_size, void* d_ws, size_t ws_size,
                              hipStream_t stream) {
  const float* head = (const float*)d_in[0];
  const float* dep = (const float*)d_in[1];
  const float* U = (const float*)d_in[2];
  const float* W = (const float*)d_in[3];
  const float* bias = (const float*)d_in[4];
  float* out = (float*)d_out;

  ushort_t* depb = (ushort_t*)d_ws;                              // 6,291,456 B
  float* t2h = (float*)((char*)d_ws + (size_t)B_ * S_ * D_ * 2);
  float* t2d = t2h + (size_t)B_ * L_ * S_;                       // 524,288 B each

  prep_kernel<<<512, 256, 0, stream>>>(head, dep, W, depb, t2h, t2d);
  main_kernel<<<B_ * L_ * 2, 256, 0, stream>>>(head, depb, U, bias, t2h, t2d, out);
}